// Round 8
// baseline (5004.527 us; speedup 1.0000x reference)
//
#include <hip/hip_runtime.h>

typedef __attribute__((ext_vector_type(8))) short short8;
typedef __attribute__((ext_vector_type(4))) float floatx4;
typedef __attribute__((ext_vector_type(2))) unsigned int uintx2;
typedef __attribute__((ext_vector_type(4))) unsigned int uintx4;
typedef unsigned short u16;

#define MFMA(a, b, c) __builtin_amdgcn_mfma_f32_16x16x32_bf16((a), (b), (c), 0, 0, 0)

__device__ __forceinline__ u16 f2bf(float f) {
  unsigned int u = __builtin_bit_cast(unsigned int, f);
  u += ((u >> 16) & 1u) + 0x7fffu;
  return (u16)(u >> 16);
}

__device__ __forceinline__ float softplus_f(float v) {
  float a = __builtin_fabsf(v);
  float e = __expf(-a);
  float l = __logf(1.0f + e);
  return __builtin_fmaxf(v, 0.0f) + l;
}

__device__ __forceinline__ unsigned int pack_sp(float lo, float hi) {
  return (unsigned int)f2bf(softplus_f(lo)) | ((unsigned int)f2bf(softplus_f(hi)) << 16);
}

// out[n*K + k] = bf16(in[k*N + n]); in is K x N row-major fp32
__global__ void transpose_cvt(const float* __restrict__ in, u16* __restrict__ out, int K, int N) {
  __shared__ float tile[32][33];
  const int bn = blockIdx.x * 32, bk = blockIdx.y * 32;
  const int tx = threadIdx.x, ty = threadIdx.y;  // 32 x 8
#pragma unroll
  for (int i = 0; i < 32; i += 8)
    tile[ty + i][tx] = in[(size_t)(bk + ty + i) * N + bn + tx];
  __syncthreads();
#pragma unroll
  for (int i = 0; i < 32; i += 8)
    out[(size_t)(bn + ty + i) * K + bk + tx] = f2bf(tile[tx][ty + i]);
}

// fp32 -> bf16, 8 elements per thread-iter
__global__ void cvt_bf16_kernel(const float* __restrict__ in, u16* __restrict__ out, long n8) {
  long i = (long)blockIdx.x * blockDim.x + threadIdx.x;
  const long stride = (long)gridDim.x * blockDim.x;
  for (; i < n8; i += stride) {
    floatx4 a = ((const floatx4*)in)[2 * i], b = ((const floatx4*)in)[2 * i + 1];
    uintx4 o;
    o.x = (unsigned)f2bf(a.x) | ((unsigned)f2bf(a.y) << 16);
    o.y = (unsigned)f2bf(a.z) | ((unsigned)f2bf(a.w) << 16);
    o.z = (unsigned)f2bf(b.x) | ((unsigned)f2bf(b.y) << 16);
    o.w = (unsigned)f2bf(b.z) | ((unsigned)f2bf(b.w) << 16);
    ((uintx4*)out)[i] = o;
  }
}

// -------- 256x256 GEMM, 1 K-half (32k) per step, 64 KB LDS, 2 blocks/CU --------
// Half-tile = [256 rows][32 k] bf16 = 16KB as permuted 16B granules.
// perm h(r) = (r>>1)&3; granule (r,g) at slot f = r*4 + (g ^ h(r)) -> b128 frag
// reads are conflict-free (8 slot classes per 16-row group), stage is 64B-coalesced.
// Per K-half: {issue ACT/W(h+1) -> vmcnt(4) -> bar -> 12 ds_reads -> 32 MFMA -> bar}.
// vmcnt(4) keeps the just-issued 4 loads in flight, retires K-half h's 4.

__device__ __forceinline__ void gld16(const void* g, void* l) {
  __builtin_amdgcn_global_load_lds((const __attribute__((address_space(1))) void*)g,
                                   (__attribute__((address_space(3))) void*)l, 16, 0, 0);
}

__device__ __forceinline__ void stage_half(const u16* __restrict__ gsrc, size_t row0, int K,
                                           int kof, u16* halfp, int wv, int lane) {
#pragma unroll
  for (int j = 0; j < 2; ++j) {
    const int G = (wv * 2 + j) * 64 + lane;  // granule slot this lane fills
    const int r = G >> 2;
    const int g = (G & 3) ^ ((r >> 1) & 3);  // granule stored here is (r, g)
    gld16(gsrc + (row0 + (size_t)r) * K + kof + g * 8, halfp + (wv * 2 + j) * 512);
  }
}

__device__ __forceinline__ short8 rdfrag(const u16* half_, int r, int g) {
  return *(const short8*)(half_ + (r * 4 + (g ^ ((r >> 1) & 3))) * 8);
}

template <int K, int EPI>  // EPI 0: softplus -> bf16 C; 1: fp32 C
__global__ __launch_bounds__(512, 4) void gemm8p(const u16* __restrict__ act,
                                                 const u16* __restrict__ wt,
                                                 void* __restrict__ Cout, int N, int nbn) {
  __shared__ u16 lds[2][2][8192];  // [buf][op 0=ACT 1=W][16KB half] = 64 KB
  const int tid = threadIdx.x, lane = tid & 63, wv = tid >> 6;
  const int l15 = lane & 15, g = lane >> 4;
  const int wvm = wv >> 2, wvn = wv & 3;  // 2 x 4 wave grid; wave owns 128m x 64n
  const int nwg = gridDim.x, o = blockIdx.x;
  const int sw = (o & 7) * (nwg >> 3) + (o >> 3);  // XCD-contiguous chunks (nwg % 8 == 0)
  const int bm = sw / nbn, bn = sw % nbn;
  const size_t am0 = (size_t)bm * 256;
  const size_t wn0 = (size_t)bn * 256;
  constexpr int H = K / 32;  // K-halves

  floatx4 acc[4][8];
  const floatx4 z4 = {0.f, 0.f, 0.f, 0.f};
#pragma unroll
  for (int t = 0; t < 4; ++t)
#pragma unroll
    for (int mt = 0; mt < 8; ++mt) acc[t][mt] = z4;

  // prologue: stage K-half 0 into buf 0
  stage_half(act, am0, K, 0, &lds[0][0][0], wv, lane);
  stage_half(wt, wn0, K, 0, &lds[0][1][0], wv, lane);

  short8 bf[8], af[4];
#pragma unroll 2
  for (int h = 0; h < H; ++h) {
    const int b = h & 1;
    if (h + 1 < H) {
      stage_half(act, am0, K, (h + 1) * 32, &lds[b ^ 1][0][0], wv, lane);
      stage_half(wt, wn0, K, (h + 1) * 32, &lds[b ^ 1][1][0], wv, lane);
      asm volatile("s_waitcnt vmcnt(4)" ::: "memory");
    } else {
      asm volatile("s_waitcnt vmcnt(0)" ::: "memory");
    }
    __builtin_amdgcn_s_barrier();
    asm volatile("" ::: "memory");
#pragma unroll
    for (int mt = 0; mt < 8; ++mt)
      bf[mt] = rdfrag(&lds[b][0][0], wvm * 128 + mt * 16 + l15, g);
#pragma unroll
    for (int t = 0; t < 4; ++t)
      af[t] = rdfrag(&lds[b][1][0], wvn * 64 + t * 16 + l15, g);
    __builtin_amdgcn_s_setprio(1);
#pragma unroll
    for (int t = 0; t < 4; ++t)
#pragma unroll
      for (int mt = 0; mt < 8; ++mt) acc[t][mt] = MFMA(af[t], bf[mt], acc[t][mt]);
    __builtin_amdgcn_s_setprio(0);
    asm volatile("" ::: "memory");
    __builtin_amdgcn_s_barrier();
    asm volatile("" ::: "memory");
  }

  // ---- epilogue: transpose C through 64 KB LDS, coalesced stores ----
  if (EPI == 0) {
    // bf16 C in two 128-row passes (64 KB each)
    u16* cl = &lds[0][0][0];
#pragma unroll
    for (int hm = 0; hm < 2; ++hm) {
      if (hm) __syncthreads();  // protect previous pass reads
      if (wvm == hm) {
#pragma unroll
        for (int t = 0; t < 4; ++t)
#pragma unroll
          for (int mt = 0; mt < 8; ++mt) {
            const int m = mt * 16 + l15;  // 0..127
            const int n0 = wvn * 64 + t * 16 + g * 4;
            const int j = n0 >> 3, hh = (n0 >> 2) & 1;
            uintx2 pk;
            pk.x = pack_sp(acc[t][mt].x, acc[t][mt].y);
            pk.y = pack_sp(acc[t][mt].z, acc[t][mt].w);
            *(uintx2*)(cl + m * 256 + ((j ^ (m & 7)) << 3) + (hh << 2)) = pk;
          }
      }
      __syncthreads();
      u16* outp = (u16*)Cout;
#pragma unroll
      for (int i = 0; i < 8; ++i) {
        const int c = i * 512 + tid;  // 16B chunk; 32 chunks/row, 128 rows
        const int m = c >> 5, j = c & 31;
        uintx4 v = *(const uintx4*)(cl + m * 256 + ((j ^ (m & 7)) << 3));
        *(uintx4*)(outp + (am0 + hm * 128 + m) * N + wn0 + j * 8) = v;
      }
    }
  } else {
    // fp32 C in four 64-row passes (64 KB each)
    float* cf = (float*)&lds[0][0][0];
#pragma unroll
    for (int q = 0; q < 4; ++q) {
      if (q) __syncthreads();
      if (wvm == (q >> 1)) {
#pragma unroll
        for (int t = 0; t < 4; ++t)
#pragma unroll
          for (int mt2 = 0; mt2 < 4; ++mt2) {
            const int mt = (q & 1) * 4 + mt2;
            const int m = mt2 * 16 + l15;  // 0..63
            const int p = (wvn * 64 + t * 16 + g * 4) >> 1;  // even 2-float slot
            *(floatx4*)(cf + m * 256 + ((p ^ ((m & 7) << 1)) << 1)) = acc[t][mt];
          }
      }
      __syncthreads();
      float* outp = (float*)Cout;
#pragma unroll
      for (int i = 0; i < 8; ++i) {
        const int c = i * 512 + tid;  // 16B chunk; 64 chunks/row, 64 rows
        const int m = c >> 6;
        const int cc = c & 63;
        const int p = cc * 2;
        floatx4 v = *(const floatx4*)(cf + m * 256 + ((p ^ ((m & 7) << 1)) << 1));
        *(floatx4*)(outp + (am0 + q * 64 + m) * N + wn0 + cc * 4) = v;
      }
    }
  }
}

// ---------------- fallback: R1 fused kernel (used only if ws is too small) ----------------
__global__ __launch_bounds__(512, 2) void mlp3_fused(const float* __restrict__ x,
                                                     const u16* __restrict__ w1t,
                                                     const u16* __restrict__ w2t,
                                                     const u16* __restrict__ w3t,
                                                     float* __restrict__ out) {
  __shared__ u16 h1s[64 * 1024];
  __shared__ u16 xs[64 * 256];
  const int tid = threadIdx.x, lane = tid & 63, wv = tid >> 6;
  const int l15 = lane & 15, g = lane >> 4;
  const size_t m0 = (size_t)blockIdx.x * 64;
  const floatx4 z4 = {0.f, 0.f, 0.f, 0.f};
  {
    const float* xp = x + m0 * 256;
#pragma unroll
    for (int r = 0; r < 8; ++r) {
      int idx4 = r * 512 + tid;
      int m = idx4 >> 6, k = (idx4 & 63) << 2;
      floatx4 v = *(const floatx4*)(xp + m * 256 + k);
      uintx2 pk;
      pk.x = (unsigned)f2bf(v.x) | ((unsigned)f2bf(v.y) << 16);
      pk.y = (unsigned)f2bf(v.z) | ((unsigned)f2bf(v.w) << 16);
      *(uintx2*)(xs + ((m * 256 + k) ^ ((m & 7) << 3))) = pk;
    }
  }
  __syncthreads();
#pragma unroll 1
  for (int c = 0; c < 4; ++c) {
    floatx4 acc[2][4];
#pragma unroll
    for (int t = 0; t < 2; ++t)
#pragma unroll
      for (int mt = 0; mt < 4; ++mt) acc[t][mt] = z4;
    const u16* p0 = w1t + (size_t)(c * 256 + wv * 32 + l15) * 256;
#pragma unroll
    for (int ks = 0; ks < 8; ++ks) {
      const int k = ks * 32 + g * 8;
      short8 a0 = *(const short8*)(p0 + k);
      short8 a1 = *(const short8*)(p0 + 16 * 256 + k);
      short8 b0 = *(const short8*)(xs + (((0 * 16 + l15) * 256 + k) ^ ((l15 & 7) << 3)));
      short8 b1 = *(const short8*)(xs + (((1 * 16 + l15) * 256 + k) ^ ((l15 & 7) << 3)));
      short8 b2 = *(const short8*)(xs + (((2 * 16 + l15) * 256 + k) ^ ((l15 & 7) << 3)));
      short8 b3 = *(const short8*)(xs + (((3 * 16 + l15) * 256 + k) ^ ((l15 & 7) << 3)));
      acc[0][0] = MFMA(a0, b0, acc[0][0]); acc[0][1] = MFMA(a0, b1, acc[0][1]);
      acc[0][2] = MFMA(a0, b2, acc[0][2]); acc[0][3] = MFMA(a0, b3, acc[0][3]);
      acc[1][0] = MFMA(a1, b0, acc[1][0]); acc[1][1] = MFMA(a1, b1, acc[1][1]);
      acc[1][2] = MFMA(a1, b2, acc[1][2]); acc[1][3] = MFMA(a1, b3, acc[1][3]);
    }
#pragma unroll
    for (int t = 0; t < 2; ++t)
#pragma unroll
      for (int mt = 0; mt < 4; ++mt) {
        const int n1 = c * 256 + wv * 32 + t * 16 + g * 4;
        const int m = mt * 16 + l15;
        uintx2 pk;
        pk.x = pack_sp(acc[t][mt].x, acc[t][mt].y);
        pk.y = pack_sp(acc[t][mt].z, acc[t][mt].w);
        *(uintx2*)(h1s + ((m * 1024 + n1) ^ ((m & 7) << 3))) = pk;
      }
  }
  __syncthreads();
  floatx4 acc3[2][4];
#pragma unroll
  for (int t = 0; t < 2; ++t)
#pragma unroll
    for (int mt = 0; mt < 4; ++mt) acc3[t][mt] = z4;
#pragma unroll 1
  for (int c2 = 0; c2 < 4; ++c2) {
    floatx4 acc2[2][4];
#pragma unroll
    for (int t = 0; t < 2; ++t)
#pragma unroll
      for (int mt = 0; mt < 4; ++mt) acc2[t][mt] = z4;
    {
      const u16* p0 = w2t + (size_t)(c2 * 256 + wv * 32 + l15) * 1024;
#pragma unroll 4
      for (int ks = 0; ks < 32; ++ks) {
        const int k = ks * 32 + g * 8;
        short8 a0 = *(const short8*)(p0 + k);
        short8 a1 = *(const short8*)(p0 + 16 * 1024 + k);
        short8 b0 = *(const short8*)(h1s + (((0 * 16 + l15) * 1024 + k) ^ ((l15 & 7) << 3)));
        short8 b1 = *(const short8*)(h1s + (((1 * 16 + l15) * 1024 + k) ^ ((l15 & 7) << 3)));
        short8 b2 = *(const short8*)(h1s + (((2 * 16 + l15) * 1024 + k) ^ ((l15 & 7) << 3)));
        short8 b3 = *(const short8*)(h1s + (((3 * 16 + l15) * 1024 + k) ^ ((l15 & 7) << 3)));
        acc2[0][0] = MFMA(a0, b0, acc2[0][0]); acc2[0][1] = MFMA(a0, b1, acc2[0][1]);
        acc2[0][2] = MFMA(a0, b2, acc2[0][2]); acc2[0][3] = MFMA(a0, b3, acc2[0][3]);
        acc2[1][0] = MFMA(a1, b0, acc2[1][0]); acc2[1][1] = MFMA(a1, b1, acc2[1][1]);
        acc2[1][2] = MFMA(a1, b2, acc2[1][2]); acc2[1][3] = MFMA(a1, b3, acc2[1][3]);
      }
    }
    __syncthreads();
#pragma unroll
    for (int t = 0; t < 2; ++t)
#pragma unroll
      for (int mt = 0; mt < 4; ++mt) {
        const int n2l = wv * 32 + t * 16 + g * 4;
        const int m = mt * 16 + l15;
        uintx2 pk;
        pk.x = pack_sp(acc2[t][mt].x, acc2[t][mt].y);
        pk.y = pack_sp(acc2[t][mt].z, acc2[t][mt].w);
        *(uintx2*)(xs + ((m * 256 + n2l) ^ ((m & 7) << 3))) = pk;
      }
    __syncthreads();
    {
      const u16* p0 = w3t + (size_t)(wv * 32 + l15) * 1024 + c2 * 256;
#pragma unroll
      for (int ks = 0; ks < 8; ++ks) {
        const int k = ks * 32 + g * 8;
        short8 a0 = *(const short8*)(p0 + k);
        short8 a1 = *(const short8*)(p0 + 16 * 1024 + k);
        short8 b0 = *(const short8*)(xs + (((0 * 16 + l15) * 256 + k) ^ ((l15 & 7) << 3)));
        short8 b1 = *(const short8*)(xs + (((1 * 16 + l15) * 256 + k) ^ ((l15 & 7) << 3)));
        short8 b2 = *(const short8*)(xs + (((2 * 16 + l15) * 256 + k) ^ ((l15 & 7) << 3)));
        short8 b3 = *(const short8*)(xs + (((3 * 16 + l15) * 256 + k) ^ ((l15 & 7) << 3)));
        acc3[0][0] = MFMA(a0, b0, acc3[0][0]); acc3[0][1] = MFMA(a0, b1, acc3[0][1]);
        acc3[0][2] = MFMA(a0, b2, acc3[0][2]); acc3[0][3] = MFMA(a0, b3, acc3[0][3]);
        acc3[1][0] = MFMA(a1, b0, acc3[1][0]); acc3[1][1] = MFMA(a1, b1, acc3[1][1]);
        acc3[1][2] = MFMA(a1, b2, acc3[1][2]); acc3[1][3] = MFMA(a1, b3, acc3[1][3]);
      }
    }
  }
#pragma unroll
  for (int t = 0; t < 2; ++t)
#pragma unroll
    for (int mt = 0; mt < 4; ++mt) {
      const int n3 = wv * 32 + t * 16 + g * 4;
      const int m = mt * 16 + l15;
      *(floatx4*)(out + (m0 + m) * 256 + n3) = acc3[t][mt];
    }
}

extern "C" void kernel_launch(void* const* d_in, const int* in_sizes, int n_in,
                              void* d_out, int out_size, void* d_ws, size_t ws_size,
                              hipStream_t stream) {
  const float* x = (const float*)d_in[0];
  const float* w1 = (const float*)d_in[1];
  const float* w2 = (const float*)d_in[2];
  const float* w3 = (const float*)d_in[3];
  float* out = (float*)d_out;
  const size_t M = 131072;

  u16* w1t = (u16*)d_ws;                      // [1024][256]
  u16* w2t = w1t + 1024 * 256;                // [1024][1024]
  u16* w3t = w2t + 1024 * 1024;               // [256][1024]
  u16* bufA = w3t + 256 * 1024;               // CM*1024 bf16 (xbf in first CM*256, then h2)
  const size_t weights_el = 1024 * 256 + 1024 * 1024 + 256 * 1024;

  // largest chunk that fits: need = weights + 2 ping-pong buffers of CM*1024 bf16
  size_t CM = 0;
  const size_t cands[5] = {65536, 32768, 16384, 8192, 4096};
  for (int i = 0; i < 5; ++i) {
    size_t need = (weights_el + 2 * cands[i] * 1024) * sizeof(u16);
    if (ws_size >= need) { CM = cands[i]; break; }
  }

  dim3 tb(32, 8);
  transpose_cvt<<<dim3(32, 8), tb, 0, stream>>>(w1, w1t, 256, 1024);
  transpose_cvt<<<dim3(32, 32), tb, 0, stream>>>(w2, w2t, 1024, 1024);
  transpose_cvt<<<dim3(8, 32), tb, 0, stream>>>(w3, w3t, 1024, 256);

  if (CM) {
    u16* bufB = bufA + CM * 1024;
    const int nchunk = (int)(M / CM);
    for (int ci = 0; ci < nchunk; ++ci) {
      const float* xc = x + (size_t)ci * CM * 256;
      float* oc = out + (size_t)ci * CM * 256;
      cvt_bf16_kernel<<<2048, 256, 0, stream>>>(xc, bufA, (long)(CM * 32));
      gemm8p<256, 0><<<(int)(CM / 256) * 4, 512, 0, stream>>>(bufA, w1t, bufB, 1024, 4);
      gemm8p<1024, 0><<<(int)(CM / 256) * 4, 512, 0, stream>>>(bufB, w2t, bufA, 1024, 4);
      gemm8p<1024, 1><<<(int)(CM / 256), 512, 0, stream>>>(bufA, w3t, oc, 256, 1);
    }
  } else {
    mlp3_fused<<<M / 64, 512, 0, stream>>>(x, w1t, w2t, w3t, out);
  }
}

// Round 9
// 676.993 us; speedup vs baseline: 7.3923x; 7.3923x over previous
//
#include <hip/hip_runtime.h>

typedef __attribute__((ext_vector_type(8))) short short8;
typedef __attribute__((ext_vector_type(4))) float floatx4;
typedef __attribute__((ext_vector_type(2))) unsigned int uintx2;
typedef __attribute__((ext_vector_type(4))) unsigned int uintx4;
typedef unsigned short u16;

#define MFMA(a, b, c) __builtin_amdgcn_mfma_f32_16x16x32_bf16((a), (b), (c), 0, 0, 0)

__device__ __forceinline__ u16 f2bf(float f) {
  unsigned int u = __builtin_bit_cast(unsigned int, f);
  u += ((u >> 16) & 1u) + 0x7fffu;
  return (u16)(u >> 16);
}

__device__ __forceinline__ float softplus_f(float v) {
  float a = __builtin_fabsf(v);
  float e = __expf(-a);
  float l = __logf(1.0f + e);
  return __builtin_fmaxf(v, 0.0f) + l;
}

__device__ __forceinline__ unsigned int pack_sp(float lo, float hi) {
  return (unsigned int)f2bf(softplus_f(lo)) | ((unsigned int)f2bf(softplus_f(hi)) << 16);
}

// out[n*K + k] = bf16(in[k*N + n]); in is K x N row-major fp32
__global__ void transpose_cvt(const float* __restrict__ in, u16* __restrict__ out, int K, int N) {
  __shared__ float tile[32][33];
  const int bn = blockIdx.x * 32, bk = blockIdx.y * 32;
  const int tx = threadIdx.x, ty = threadIdx.y;  // 32 x 8
#pragma unroll
  for (int i = 0; i < 32; i += 8)
    tile[ty + i][tx] = in[(size_t)(bk + ty + i) * N + bn + tx];
  __syncthreads();
#pragma unroll
  for (int i = 0; i < 32; i += 8)
    out[(size_t)(bn + ty + i) * K + bk + tx] = f2bf(tile[tx][ty + i]);
}

// fp32 -> bf16, 8 elements per thread-iter
__global__ void cvt_bf16_kernel(const float* __restrict__ in, u16* __restrict__ out, long n8) {
  long i = (long)blockIdx.x * blockDim.x + threadIdx.x;
  const long stride = (long)gridDim.x * blockDim.x;
  for (; i < n8; i += stride) {
    floatx4 a = ((const floatx4*)in)[2 * i], b = ((const floatx4*)in)[2 * i + 1];
    uintx4 o;
    o.x = (unsigned)f2bf(a.x) | ((unsigned)f2bf(a.y) << 16);
    o.y = (unsigned)f2bf(a.z) | ((unsigned)f2bf(a.w) << 16);
    o.z = (unsigned)f2bf(b.x) | ((unsigned)f2bf(b.y) << 16);
    o.w = (unsigned)f2bf(b.z) | ((unsigned)f2bf(b.w) << 16);
    ((uintx4*)out)[i] = o;
  }
}

// -------- 256x256 GEMM (C = act @ wt^T), 1 phase per 32-k half, 128 KB LDS --------
// Half-tile = [256 rows][32 k] bf16 = 16KB as permuted 16B granules.
// perm h(r)=(r>>1)&3; granule (r,g) at slot f = r*4 + (g ^ h(r)): b128 frag reads
// conflict-free, staging 64B-coalesced. 4 half-slots rotate: phase p consumes
// slot p&3 (af) and prefetches bf from slot (p+1)&3; stages half p+2 into (p+2)&3.
// vmcnt(4) retires the half the NEXT phase reads; never 0 mid-loop.

__device__ __forceinline__ void gld16(const void* g, void* l) {
  __builtin_amdgcn_global_load_lds((const __attribute__((address_space(1))) void*)g,
                                   (__attribute__((address_space(3))) void*)l, 16, 0, 0);
}

template <int K, int EPI>  // EPI 0: softplus -> bf16 C; 1: fp32 C
__global__ __launch_bounds__(512, 2) void gemmk(const u16* __restrict__ act,
                                                const u16* __restrict__ wt,
                                                void* __restrict__ Cout, int N, int nbn) {
  __shared__ u16 lds[4][2][8192];  // [half-slot][op 0=ACT 1=W][16KB] = 128 KB
  u16* L = &lds[0][0][0];
  const int tid = threadIdx.x, lane = tid & 63, wv = tid >> 6;
  const int l15 = lane & 15, g = lane >> 4;
  const int wvm = wv >> 2, wvn = wv & 3;  // 2 x 4 wave grid; wave owns 128m x 64n
  const int nwg = gridDim.x, o = blockIdx.x;
  const int sw = (o & 7) * (nwg >> 3) + (o >> 3);  // XCD-contiguous chunks (nwg % 8 == 0)
  const int bm = sw / nbn, bn = sw % nbn;
  const size_t am0 = (size_t)bm * 256;
  const size_t wn0 = (size_t)bn * 256;
  constexpr int H = K / 32;  // 32-k halves

  // ---- loop-invariant fragment byte/elem offsets (within a 16KB half) ----
  int bfo[8], afo[4];
#pragma unroll
  for (int mt = 0; mt < 8; ++mt) {
    const int r = wvm * 128 + mt * 16 + l15;
    bfo[mt] = (r * 4 + (g ^ ((r >> 1) & 3))) * 8;
  }
#pragma unroll
  for (int t = 0; t < 4; ++t) {
    const int r = wvn * 64 + t * 16 + l15;
    afo[t] = (r * 4 + (g ^ ((r >> 1) & 3))) * 8;
  }
  // ---- loop-invariant stage source pointers (per lane) and LDS dest offsets ----
  const u16 *asrc0, *asrc1, *wsrc0, *wsrc1;
  {
    const int G0 = (wv * 2 + 0) * 64 + lane, r0 = G0 >> 2, g0 = (G0 & 3) ^ ((r0 >> 1) & 3);
    const int G1 = (wv * 2 + 1) * 64 + lane, r1 = G1 >> 2, g1 = (G1 & 3) ^ ((r1 >> 1) & 3);
    asrc0 = act + (am0 + r0) * (size_t)K + g0 * 8;
    asrc1 = act + (am0 + r1) * (size_t)K + g1 * 8;
    wsrc0 = wt + (wn0 + r0) * (size_t)K + g0 * 8;
    wsrc1 = wt + (wn0 + r1) * (size_t)K + g1 * 8;
  }
  const int d0 = (wv * 2 + 0) * 512, d1 = (wv * 2 + 1) * 512;

#define STAGE_HALF(hh)                                                \
  {                                                                   \
    const int s_ = ((hh) & 3) * 16384;                                \
    const int ko_ = (hh) * 32;                                        \
    gld16(asrc0 + ko_, L + s_ + d0);                                  \
    gld16(asrc1 + ko_, L + s_ + d1);                                  \
    gld16(wsrc0 + ko_, L + s_ + 8192 + d0);                           \
    gld16(wsrc1 + ko_, L + s_ + 8192 + d1);                           \
  }

  floatx4 acc[4][8];
  const floatx4 z4 = {0.f, 0.f, 0.f, 0.f};
#pragma unroll
  for (int t = 0; t < 4; ++t)
#pragma unroll
    for (int mt = 0; mt < 8; ++mt) acc[t][mt] = z4;

  short8 bfA[8], bfB[8], af[4];

  // prologue: stage halves 0 and 1; establish half 0; preload bfA(half 0)
  STAGE_HALF(0)
  STAGE_HALF(1)
  asm volatile("s_waitcnt vmcnt(4)" ::: "memory");
  __builtin_amdgcn_s_barrier();
  asm volatile("" ::: "memory");
#pragma unroll
  for (int mt = 0; mt < 8; ++mt) bfA[mt] = *(const short8*)(L + bfo[mt]);

#define PHASEX(p_, CUR, NXT)                                                          \
  {                                                                                   \
    if ((p_) + 2 < H) {                                                               \
      STAGE_HALF((p_) + 2)                                                            \
      asm volatile("s_waitcnt vmcnt(4)" ::: "memory");                                \
    } else {                                                                          \
      asm volatile("s_waitcnt vmcnt(0)" ::: "memory");                                \
    }                                                                                 \
    __builtin_amdgcn_s_barrier();                                                     \
    asm volatile("" ::: "memory");                                                    \
    const int sc_ = ((p_) & 3) * 16384, sn_ = (((p_) + 1) & 3) * 16384;               \
    _Pragma("unroll") for (int t = 0; t < 4; ++t)                                     \
        af[t] = *(const short8*)(L + sc_ + 8192 + afo[t]);                            \
    if ((p_) + 1 < H) {                                                               \
      _Pragma("unroll") for (int mt = 0; mt < 8; ++mt)                                \
          NXT[mt] = *(const short8*)(L + sn_ + bfo[mt]);                              \
    }                                                                                 \
    __builtin_amdgcn_s_setprio(1);                                                    \
    _Pragma("unroll") for (int t = 0; t < 4; ++t)                                     \
        _Pragma("unroll") for (int mt = 0; mt < 8; ++mt)                              \
            acc[t][mt] = MFMA(af[t], CUR[mt], acc[t][mt]);                            \
    __builtin_amdgcn_s_setprio(0);                                                    \
    asm volatile("" ::: "memory");                                                    \
    __builtin_amdgcn_s_barrier();                                                     \
    asm volatile("" ::: "memory");                                                    \
  }

#pragma unroll 1
  for (int it = 0; it < H / 2; ++it) {
    PHASEX(2 * it, bfA, bfB)
    PHASEX(2 * it + 1, bfB, bfA)
  }
#undef PHASEX
#undef STAGE_HALF

  // ---- epilogue: all gld16 retired (vmcnt(0) in tail) + final barrier passed ----
  if (EPI == 0) {
    // bf16 C: full 256x256 tile = 128 KB, one pass. 8B-granule XOR swizzle.
    u16* cl = L;
#pragma unroll
    for (int t = 0; t < 4; ++t)
#pragma unroll
      for (int mt = 0; mt < 8; ++mt) {
        const int m = wvm * 128 + mt * 16 + l15;
        const int n0 = wvn * 64 + t * 16 + g * 4;
        const int j = n0 >> 3, hh = (n0 >> 2) & 1;
        uintx2 pk;
        pk.x = pack_sp(acc[t][mt].x, acc[t][mt].y);
        pk.y = pack_sp(acc[t][mt].z, acc[t][mt].w);
        *(uintx2*)(cl + m * 256 + ((j ^ (m & 7)) << 3) + (hh << 2)) = pk;
      }
    __syncthreads();
    u16* outp = (u16*)Cout;
#pragma unroll
    for (int i = 0; i < 16; ++i) {
      const int c = i * 512 + tid;  // 16B chunk; 32 chunks/row, 256 rows
      const int m = c >> 5, j = c & 31;
      uintx4 v = *(const uintx4*)(cl + m * 256 + ((j ^ (m & 7)) << 3));
      *(uintx4*)(outp + (am0 + m) * N + wn0 + j * 8) = v;
    }
  } else {
    // fp32 C in two 128-row passes (128 KB each). 8B(2-float)-slot XOR swizzle.
    float* cf = (float*)L;
#pragma unroll
    for (int hm = 0; hm < 2; ++hm) {
      if (hm) __syncthreads();  // protect previous pass reads
      if (wvm == hm) {
#pragma unroll
        for (int t = 0; t < 4; ++t)
#pragma unroll
          for (int mt = 0; mt < 8; ++mt) {
            const int m = mt * 16 + l15;                     // 0..127
            const int p = (wvn * 64 + t * 16 + g * 4) >> 1;  // even 2-float slot
            *(floatx4*)(cf + m * 256 + ((p ^ ((m & 7) << 1)) << 1)) = acc[t][mt];
          }
      }
      __syncthreads();
      float* outp = (float*)Cout;
#pragma unroll
      for (int i = 0; i < 16; ++i) {
        const int c = i * 512 + tid;  // 16B chunk; 64 chunks/row, 128 rows
        const int m = c >> 6;
        const int cc = c & 63;
        const int p = cc * 2;
        floatx4 v = *(const floatx4*)(cf + m * 256 + ((p ^ ((m & 7) << 1)) << 1));
        *(floatx4*)(outp + (am0 + hm * 128 + m) * N + wn0 + cc * 4) = v;
      }
    }
  }
}

// ---------------- fallback: R1 fused kernel (used only if ws is too small) ----------------
__global__ __launch_bounds__(512, 2) void mlp3_fused(const float* __restrict__ x,
                                                     const u16* __restrict__ w1t,
                                                     const u16* __restrict__ w2t,
                                                     const u16* __restrict__ w3t,
                                                     float* __restrict__ out) {
  __shared__ u16 h1s[64 * 1024];
  __shared__ u16 xs[64 * 256];
  const int tid = threadIdx.x, lane = tid & 63, wv = tid >> 6;
  const int l15 = lane & 15, g = lane >> 4;
  const size_t m0 = (size_t)blockIdx.x * 64;
  const floatx4 z4 = {0.f, 0.f, 0.f, 0.f};
  {
    const float* xp = x + m0 * 256;
#pragma unroll
    for (int r = 0; r < 8; ++r) {
      int idx4 = r * 512 + tid;
      int m = idx4 >> 6, k = (idx4 & 63) << 2;
      floatx4 v = *(const floatx4*)(xp + m * 256 + k);
      uintx2 pk;
      pk.x = (unsigned)f2bf(v.x) | ((unsigned)f2bf(v.y) << 16);
      pk.y = (unsigned)f2bf(v.z) | ((unsigned)f2bf(v.w) << 16);
      *(uintx2*)(xs + ((m * 256 + k) ^ ((m & 7) << 3))) = pk;
    }
  }
  __syncthreads();
#pragma unroll 1
  for (int c = 0; c < 4; ++c) {
    floatx4 acc[2][4];
#pragma unroll
    for (int t = 0; t < 2; ++t)
#pragma unroll
      for (int mt = 0; mt < 4; ++mt) acc[t][mt] = z4;
    const u16* p0 = w1t + (size_t)(c * 256 + wv * 32 + l15) * 256;
#pragma unroll
    for (int ks = 0; ks < 8; ++ks) {
      const int k = ks * 32 + g * 8;
      short8 a0 = *(const short8*)(p0 + k);
      short8 a1 = *(const short8*)(p0 + 16 * 256 + k);
      short8 b0 = *(const short8*)(xs + (((0 * 16 + l15) * 256 + k) ^ ((l15 & 7) << 3)));
      short8 b1 = *(const short8*)(xs + (((1 * 16 + l15) * 256 + k) ^ ((l15 & 7) << 3)));
      short8 b2 = *(const short8*)(xs + (((2 * 16 + l15) * 256 + k) ^ ((l15 & 7) << 3)));
      short8 b3 = *(const short8*)(xs + (((3 * 16 + l15) * 256 + k) ^ ((l15 & 7) << 3)));
      acc[0][0] = MFMA(a0, b0, acc[0][0]); acc[0][1] = MFMA(a0, b1, acc[0][1]);
      acc[0][2] = MFMA(a0, b2, acc[0][2]); acc[0][3] = MFMA(a0, b3, acc[0][3]);
      acc[1][0] = MFMA(a1, b0, acc[1][0]); acc[1][1] = MFMA(a1, b1, acc[1][1]);
      acc[1][2] = MFMA(a1, b2, acc[1][2]); acc[1][3] = MFMA(a1, b3, acc[1][3]);
    }
#pragma unroll
    for (int t = 0; t < 2; ++t)
#pragma unroll
      for (int mt = 0; mt < 4; ++mt) {
        const int n1 = c * 256 + wv * 32 + t * 16 + g * 4;
        const int m = mt * 16 + l15;
        uintx2 pk;
        pk.x = pack_sp(acc[t][mt].x, acc[t][mt].y);
        pk.y = pack_sp(acc[t][mt].z, acc[t][mt].w);
        *(uintx2*)(h1s + ((m * 1024 + n1) ^ ((m & 7) << 3))) = pk;
      }
  }
  __syncthreads();
  floatx4 acc3[2][4];
#pragma unroll
  for (int t = 0; t < 2; ++t)
#pragma unroll
    for (int mt = 0; mt < 4; ++mt) acc3[t][mt] = z4;
#pragma unroll 1
  for (int c2 = 0; c2 < 4; ++c2) {
    floatx4 acc2[2][4];
#pragma unroll
    for (int t = 0; t < 2; ++t)
#pragma unroll
      for (int mt = 0; mt < 4; ++mt) acc2[t][mt] = z4;
    {
      const u16* p0 = w2t + (size_t)(c2 * 256 + wv * 32 + l15) * 1024;
#pragma unroll 4
      for (int ks = 0; ks < 32; ++ks) {
        const int k = ks * 32 + g * 8;
        short8 a0 = *(const short8*)(p0 + k);
        short8 a1 = *(const short8*)(p0 + 16 * 1024 + k);
        short8 b0 = *(const short8*)(h1s + (((0 * 16 + l15) * 1024 + k) ^ ((l15 & 7) << 3)));
        short8 b1 = *(const short8*)(h1s + (((1 * 16 + l15) * 1024 + k) ^ ((l15 & 7) << 3)));
        short8 b2 = *(const short8*)(h1s + (((2 * 16 + l15) * 1024 + k) ^ ((l15 & 7) << 3)));
        short8 b3 = *(const short8*)(h1s + (((3 * 16 + l15) * 1024 + k) ^ ((l15 & 7) << 3)));
        acc2[0][0] = MFMA(a0, b0, acc2[0][0]); acc2[0][1] = MFMA(a0, b1, acc2[0][1]);
        acc2[0][2] = MFMA(a0, b2, acc2[0][2]); acc2[0][3] = MFMA(a0, b3, acc2[0][3]);
        acc2[1][0] = MFMA(a1, b0, acc2[1][0]); acc2[1][1] = MFMA(a1, b1, acc2[1][1]);
        acc2[1][2] = MFMA(a1, b2, acc2[1][2]); acc2[1][3] = MFMA(a1, b3, acc2[1][3]);
      }
    }
    __syncthreads();
#pragma unroll
    for (int t = 0; t < 2; ++t)
#pragma unroll
      for (int mt = 0; mt < 4; ++mt) {
        const int n2l = wv * 32 + t * 16 + g * 4;
        const int m = mt * 16 + l15;
        uintx2 pk;
        pk.x = pack_sp(acc2[t][mt].x, acc2[t][mt].y);
        pk.y = pack_sp(acc2[t][mt].z, acc2[t][mt].w);
        *(uintx2*)(xs + ((m * 256 + n2l) ^ ((m & 7) << 3))) = pk;
      }
    __syncthreads();
    {
      const u16* p0 = w3t + (size_t)(wv * 32 + l15) * 1024 + c2 * 256;
#pragma unroll
      for (int ks = 0; ks < 8; ++ks) {
        const int k = ks * 32 + g * 8;
        short8 a0 = *(const short8*)(p0 + k);
        short8 a1 = *(const short8*)(p0 + 16 * 1024 + k);
        short8 b0 = *(const short8*)(xs + (((0 * 16 + l15) * 256 + k) ^ ((l15 & 7) << 3)));
        short8 b1 = *(const short8*)(xs + (((1 * 16 + l15) * 256 + k) ^ ((l15 & 7) << 3)));
        short8 b2 = *(const short8*)(xs + (((2 * 16 + l15) * 256 + k) ^ ((l15 & 7) << 3)));
        short8 b3 = *(const short8*)(xs + (((3 * 16 + l15) * 256 + k) ^ ((l15 & 7) << 3)));
        acc3[0][0] = MFMA(a0, b0, acc3[0][0]); acc3[0][1] = MFMA(a0, b1, acc3[0][1]);
        acc3[0][2] = MFMA(a0, b2, acc3[0][2]); acc3[0][3] = MFMA(a0, b3, acc3[0][3]);
        acc3[1][0] = MFMA(a1, b0, acc3[1][0]); acc3[1][1] = MFMA(a1, b1, acc3[1][1]);
        acc3[1][2] = MFMA(a1, b2, acc3[1][2]); acc3[1][3] = MFMA(a1, b3, acc3[1][3]);
      }
    }
  }
#pragma unroll
  for (int t = 0; t < 2; ++t)
#pragma unroll
    for (int mt = 0; mt < 4; ++mt) {
      const int n3 = wv * 32 + t * 16 + g * 4;
      const int m = mt * 16 + l15;
      *(floatx4*)(out + (m0 + m) * 256 + n3) = acc3[t][mt];
    }
}

extern "C" void kernel_launch(void* const* d_in, const int* in_sizes, int n_in,
                              void* d_out, int out_size, void* d_ws, size_t ws_size,
                              hipStream_t stream) {
  const float* x = (const float*)d_in[0];
  const float* w1 = (const float*)d_in[1];
  const float* w2 = (const float*)d_in[2];
  const float* w3 = (const float*)d_in[3];
  float* out = (float*)d_out;
  const size_t M = 131072;

  u16* w1t = (u16*)d_ws;                      // [1024][256]
  u16* w2t = w1t + 1024 * 256;                // [1024][1024]
  u16* w3t = w2t + 1024 * 1024;               // [256][1024]
  u16* bufA = w3t + 256 * 1024;               // CM*1024 bf16 (xbf in first CM*256, then h2)
  const size_t weights_el = 1024 * 256 + 1024 * 1024 + 256 * 1024;

  // largest chunk that fits: need = weights + 2 ping-pong buffers of CM*1024 bf16
  size_t CM = 0;
  const size_t cands[5] = {65536, 32768, 16384, 8192, 4096};
  for (int i = 0; i < 5; ++i) {
    size_t need = (weights_el + 2 * cands[i] * 1024) * sizeof(u16);
    if (ws_size >= need) { CM = cands[i]; break; }
  }

  dim3 tb(32, 8);
  transpose_cvt<<<dim3(32, 8), tb, 0, stream>>>(w1, w1t, 256, 1024);
  transpose_cvt<<<dim3(32, 32), tb, 0, stream>>>(w2, w2t, 1024, 1024);
  transpose_cvt<<<dim3(8, 32), tb, 0, stream>>>(w3, w3t, 1024, 256);

  if (CM) {
    u16* bufB = bufA + CM * 1024;
    const int nchunk = (int)(M / CM);
    for (int ci = 0; ci < nchunk; ++ci) {
      const float* xc = x + (size_t)ci * CM * 256;
      float* oc = out + (size_t)ci * CM * 256;
      cvt_bf16_kernel<<<2048, 256, 0, stream>>>(xc, bufA, (long)(CM * 32));
      gemmk<256, 0><<<(int)(CM / 256) * 4, 512, 0, stream>>>(bufA, w1t, bufB, 1024, 4);
      gemmk<1024, 0><<<(int)(CM / 256) * 4, 512, 0, stream>>>(bufB, w2t, bufA, 1024, 4);
      gemmk<1024, 1><<<(int)(CM / 256), 512, 0, stream>>>(bufA, w3t, oc, 256, 1);
    }
  } else {
    mlp3_fused<<<M / 64, 512, 0, stream>>>(x, w1t, w2t, w3t, out);
  }
}